// Round 4
// baseline (247.589 us; speedup 1.0000x reference)
//
#include <hip/hip_runtime.h>
#include <math.h>

// Problem constants (fixed by reference)
constexpr int BB = 4;
constexpr int TT = 2048;
constexpr int CC = 1024;
constexpr int NHH = 16;
constexpr int HDD = 64;    // head dim
constexpr int C3 = 3 * CC; // 3072

typedef __bf16 bf16x8 __attribute__((ext_vector_type(8)));
typedef float  f32x4  __attribute__((ext_vector_type(4)));

__device__ __forceinline__ unsigned short f2bf(float x) {
    union { float f; unsigned u; } v; v.f = x;
    unsigned r = v.u + 0x7fffu + ((v.u >> 16) & 1u);  // RNE
    return (unsigned short)(r >> 16);
}

#define AS1(p) ((const __attribute__((address_space(1))) void*)(p))
#define AS3(p) ((__attribute__((address_space(3))) void*)(p))

constexpr float SM2 = 17.312340490667561f;    // 12 * log2(e)
constexpr float QSCALE = 0.18033688011112043f; // 0.125 * log2(e)

// ---------------------------------------------------------------------------
// prep: (a) x fp32->bf16 cast, (b) W_qkv transpose+cast, (c) W_out
// transpose+cast, (d) kbias = (mask-1)*1e38 - SM2 (fp32) — block-range dispatch.
// ---------------------------------------------------------------------------
constexpr int CAST_BLOCKS = (BB * TT * CC / 4) / 256;          // 8192
constexpr int TQKV_BLOCKS = (C3 / 64) * (CC / 64);             // 768
constexpr int TOUT_BLOCKS = (CC / 64) * (CC / 64);             // 256
constexpr int KB_BLOCKS   = (BB * TT) / 256;                   // 32

__global__ __launch_bounds__(256) void prep(
    const float* __restrict__ x,
    const float* __restrict__ Wqkv,
    const float* __restrict__ Wout,
    const float* __restrict__ amask,
    unsigned short* __restrict__ xb,
    unsigned short* __restrict__ Wqkvt,
    unsigned short* __restrict__ Woutt,
    float* __restrict__ kbias)
{
    __shared__ float tile[64][65];
    const int bid = blockIdx.x;
    const int t = threadIdx.x;

    if (bid < CAST_BLOCKS) {
        const int i = bid * 256 + t;
        float4 v = ((const float4*)x)[i];
        ushort4 o;
        o.x = f2bf(v.x); o.y = f2bf(v.y); o.z = f2bf(v.z); o.w = f2bf(v.w);
        ((ushort4*)xb)[i] = o;
        return;
    }
    if (bid >= CAST_BLOCKS + TQKV_BLOCKS + TOUT_BLOCKS) {
        const int i = (bid - CAST_BLOCKS - TQKV_BLOCKS - TOUT_BLOCKS) * 256 + t;
        kbias[i] = (amask[i] - 1.0f) * 1.0e38f - SM2;
        return;
    }

    const float* src; unsigned short* dst; int R, Cn, r0, c0;
    if (bid < CAST_BLOCKS + TQKV_BLOCKS) {
        const int tb = bid - CAST_BLOCKS;
        src = Wqkv; dst = Wqkvt; R = CC; Cn = C3;
        c0 = (tb % (C3 / 64)) * 64; r0 = (tb / (C3 / 64)) * 64;
    } else {
        const int tb = bid - CAST_BLOCKS - TQKV_BLOCKS;
        src = Wout; dst = Woutt; R = CC; Cn = CC;
        c0 = (tb % (CC / 64)) * 64; r0 = (tb / (CC / 64)) * 64;
    }

    const int lr = t >> 4, lc = (t & 15) * 4;
    #pragma unroll
    for (int s = 0; s < 4; ++s) {
        float4 v = *(const float4*)&src[(size_t)(r0 + lr + s * 16) * Cn + c0 + lc];
        tile[lr + s * 16][lc + 0] = v.x;
        tile[lr + s * 16][lc + 1] = v.y;
        tile[lr + s * 16][lc + 2] = v.z;
        tile[lr + s * 16][lc + 3] = v.w;
    }
    __syncthreads();
    const int oi = t >> 2, oc = (t & 3) * 16;
    unsigned short buf[16];
    #pragma unroll
    for (int u = 0; u < 16; ++u)
        buf[u] = f2bf(tile[oc + u][oi]);
    unsigned short* d = &dst[(size_t)(c0 + oi) * R + r0 + oc];
    *(uint4*)(d + 0) = *(uint4*)&buf[0];
    *(uint4*)(d + 8) = *(uint4*)&buf[8];
}

// ---------------------------------------------------------------------------
// QKV GEMM v3: 256x192 tile, 512 threads (8 waves as 2M x 4N), per-wave
// output 128x48 (acc[8][3]) — 48 MFMA : 22 ds_read_b128 per K-step vs
// 32:24 at the 128^2 structure (which ceilinged at ~820 TF). LDS 112 KB
// (1 block/CU, 2 waves/SIMD = m201's occupancy). Counted-vmcnt two-barrier
// pipeline carried over verbatim (7 loads/K-tile -> vmcnt(7) steady state).
// Grid 512 = exactly 2 even passes at 1 block/CU. XCD-grouped by M-band:
// XCD i owns mt 4i..4i+3 (A-slice 2 MB L2-resident); B (6 MB) L3-absorbed.
// Epilogue region-dispatches per 16-col fragment (192-wide tiles straddle
// the Q/K/V boundaries at n=1024/2048; boundaries are 16-aligned so no
// fragment straddles): Q -> Qp[m][C] scaled, K -> Kp packed, V -> Vtp
// transposed.
// ---------------------------------------------------------------------------
__global__ __launch_bounds__(512, 2) void gemm_qkv(
    const unsigned short* __restrict__ A,   // [8192][1024] bf16 (xb)
    const unsigned short* __restrict__ Bt,  // [3072][1024] bf16 (Wqkvt)
    const float* __restrict__ bias,         // [3072]
    unsigned short* __restrict__ Qp,
    unsigned short* __restrict__ Kp,
    unsigned short* __restrict__ Vtp)
{
    __shared__ alignas(16) unsigned short As[2][256 * 64];  // 64 KB
    __shared__ alignas(16) unsigned short Bs[2][192 * 64];  // 48 KB

    const int tid  = threadIdx.x;
    const int w    = tid >> 6;        // 0..7
    const int lane = tid & 63;
    const int quad = lane >> 4;
    const int col  = lane & 15;
    const int wr = w >> 2, wc = w & 3;   // 2M x 4N wave grid

    // XCD-grouped decode (bijective over 512 blocks)
    const int lin = blockIdx.x;
    const int xcd = lin & 7, idx = lin >> 3;
    const int mt = xcd * 4 + (idx & 3);   // 0..31
    const int nt = idx >> 2;              // 0..15
    const int m0 = mt * 256, n0 = nt * 192;

    f32x4 acc[8][3];
    #pragma unroll
    for (int i = 0; i < 8; ++i)
        #pragma unroll
        for (int j = 0; j < 3; ++j)
            #pragma unroll
            for (int r = 0; r < 4; ++r)
                acc[i][j][r] = 0.0f;

    const int srow = tid >> 3;   // 0..63
    const int spos = tid & 7;
    const int sch  = spos ^ (srow & 7);
    char* AsB = (char*)&As[0][0];
    char* BsB = (char*)&Bs[0][0];

    constexpr int K  = CC;       // 1024
    constexpr int nk = K / 64;   // 16

    // DMA one 64-K tile: A 256x64 (4 issues) + B 192x64 (3 issues), 16B/lane
    auto DMA = [&](int kt, int buf) {
        const int k0 = kt << 6;
        #pragma unroll
        for (int i = 0; i < 4; ++i)
            __builtin_amdgcn_global_load_lds(
                AS1(A + (size_t)(m0 + srow + 64 * i) * K + k0 + sch * 8),
                AS3(AsB + buf * 32768 + i * 8192 + w * 1024), 16, 0, 0);
        #pragma unroll
        for (int i = 0; i < 3; ++i)
            __builtin_amdgcn_global_load_lds(
                AS1(Bt + (size_t)(n0 + srow + 64 * i) * K + k0 + sch * 8),
                AS3(BsB + buf * 24576 + i * 8192 + w * 1024), 16, 0, 0);
    };

    // prologue: tiles 0 and 1 in flight
    DMA(0, 0);
    DMA(1, 1);
    asm volatile("s_waitcnt vmcnt(7)" ::: "memory");   // tile 0 landed
    __builtin_amdgcn_s_barrier();

    for (int kt = 0; kt < nk; ++kt) {
        const int cur = kt & 1;
        const unsigned short* as = &As[cur][0];
        const unsigned short* bs = &Bs[cur][0];

        #pragma unroll
        for (int ks = 0; ks < 2; ++ks) {
            bf16x8 af[8], bf[3];
            #pragma unroll
            for (int i = 0; i < 8; ++i) {
                const int ra = wr * 128 + i * 16 + col;
                af[i] = *(const bf16x8*)&as[ra * 64 + ((quad + ks * 4) ^ (col & 7)) * 8];
            }
            #pragma unroll
            for (int j = 0; j < 3; ++j) {
                const int rb = wc * 48 + j * 16 + col;
                bf[j] = *(const bf16x8*)&bs[rb * 64 + ((quad + ks * 4) ^ (col & 7)) * 8];
            }
            #pragma unroll
            for (int i = 0; i < 8; ++i)
                #pragma unroll
                for (int j = 0; j < 3; ++j)
                    acc[i][j] = __builtin_amdgcn_mfma_f32_16x16x32_bf16(af[i], bf[j], acc[i][j], 0, 0, 0);
        }

        // barrier 1: all waves done reading buf[cur] -> safe to overwrite
        __builtin_amdgcn_s_barrier();
        if (kt + 2 < nk) {
            DMA(kt + 2, cur);
            // tile kt+1 landed; tile kt+2's 7 loads stay in flight
            asm volatile("s_waitcnt vmcnt(7)" ::: "memory");
        } else {
            asm volatile("s_waitcnt vmcnt(0)" ::: "memory");
        }
        // barrier 2: buf[cur^1] published to all waves
        __builtin_amdgcn_s_barrier();
    }

    // epilogue: per 16-col fragment region dispatch (Q / K / V)
    #pragma unroll
    for (int j = 0; j < 3; ++j) {
        const int n = n0 + wc * 48 + j * 16 + col;
        const float bn = bias[n];
        if (n < CC) {
            #pragma unroll
            for (int i = 0; i < 8; ++i) {
                const int mb = m0 + wr * 128 + i * 16 + quad * 4;
                #pragma unroll
                for (int r = 0; r < 4; ++r)
                    Qp[(size_t)(mb + r) * CC + n] = f2bf((acc[i][j][r] + bn) * QSCALE);
            }
        } else if (n < 2 * CC) {
            const int hh = (n - CC) >> 6, dd = (n - CC) & 63;
            #pragma unroll
            for (int i = 0; i < 8; ++i) {
                const int mb = m0 + wr * 128 + i * 16 + quad * 4;
                const int bidx = mb >> 11, tloc = mb & 2047;
                #pragma unroll
                for (int r = 0; r < 4; ++r)
                    Kp[(((size_t)bidx * NHH + hh) * TT + tloc + r) * HDD + dd] =
                        f2bf(acc[i][j][r] + bn);
            }
        } else {
            const int hh = (n - 2 * CC) >> 6, dd = (n - 2 * CC) & 63;
            #pragma unroll
            for (int i = 0; i < 8; ++i) {
                const int mb = m0 + wr * 128 + i * 16 + quad * 4;
                const int bidx = mb >> 11, tloc = mb & 2047;
                const int ktile = tloc >> 6, tc = tloc & 63;
                unsigned short pk[4];
                #pragma unroll
                for (int r = 0; r < 4; ++r)
                    pk[r] = f2bf(acc[i][j][r] + bn);
                *(uint2*)&Vtp[((((size_t)bidx * NHH + hh) * 32 + ktile) * HDD + dd) * 64 + tc] =
                    *(const uint2*)pk;
            }
        }
    }
}

// ---------------------------------------------------------------------------
// bf16 MFMA GEMM (128x128, counted-vmcnt dbuf) — out-projection only.
// ---------------------------------------------------------------------------
template<bool VSPLIT>
__global__ __launch_bounds__(256, 2) void gemm_bt_mfma(
    const unsigned short* __restrict__ A,   // [M][K]
    const unsigned short* __restrict__ Bt,  // [N][K]
    const float* __restrict__ bias,
    float* __restrict__ OutF,
    unsigned short* __restrict__ Qp,
    unsigned short* __restrict__ Kp,
    unsigned short* __restrict__ Vtp,
    int M, int N, int K, float qscale)
{
    __shared__ alignas(16) unsigned short As[2][128 * 64];  // 32 KB
    __shared__ alignas(16) unsigned short Bs[2][128 * 64];  // 32 KB

    const int tid  = threadIdx.x;
    const int w    = tid >> 6;
    const int lane = tid & 63;
    const int quad = lane >> 4;
    const int col  = lane & 15;

    // XCD-grouped decode (bijective): each XCD gets a contiguous band of
    // 8 M-tiles.
    const int nX  = gridDim.x;
    const int lin = blockIdx.y * nX + blockIdx.x;
    const int pos = lin >> 3;
    const int mt  = ((lin & 7) << 3) | (pos & 7);
    const int nt  = pos >> 3;
    const int m0 = mt * 128, n0 = nt * 128;
    const int wr = w >> 1, wc = w & 1;

    f32x4 acc[4][4];
    #pragma unroll
    for (int i = 0; i < 4; ++i)
        #pragma unroll
        for (int j = 0; j < 4; ++j)
            #pragma unroll
            for (int r = 0; r < 4; ++r)
                acc[i][j][r] = 0.0f;

    const int srow = tid >> 3;   // 0..31
    const int spos = tid & 7;
    char* AsB = (char*)&As[0][0];
    char* BsB = (char*)&Bs[0][0];

    const int nk = K >> 6;

    auto DMA = [&](int kt, int buf) {
        const int k0 = kt << 6;
        #pragma unroll
        for (int i = 0; i < 4; ++i) {
            const int row = srow + 32 * i;
            const int sch = spos ^ (row & 7);
            __builtin_amdgcn_global_load_lds(
                AS1(A + (size_t)(m0 + row) * K + k0 + sch * 8),
                AS3(AsB + buf * 16384 + i * 4096 + w * 1024), 16, 0, 0);
            __builtin_amdgcn_global_load_lds(
                AS1(Bt + (size_t)(n0 + row) * K + k0 + sch * 8),
                AS3(BsB + buf * 16384 + i * 4096 + w * 1024), 16, 0, 0);
        }
    };

    DMA(0, 0);
    DMA(1, 1);
    asm volatile("s_waitcnt vmcnt(8)" ::: "memory");   // tile 0 landed
    __builtin_amdgcn_s_barrier();

    for (int kt = 0; kt < nk; ++kt) {
        const int cur = kt & 1;
        const unsigned short* as = &As[cur][0];
        const unsigned short* bs = &Bs[cur][0];

        #pragma unroll
        for (int ks = 0; ks < 2; ++ks) {
            bf16x8 af[4], bf[4];
            #pragma unroll
            for (int i = 0; i < 4; ++i) {
                const int ra = wr * 64 + i * 16 + col;
                const int pa = ((quad + ks * 4) ^ (ra & 7)) * 8;
                af[i] = *(const bf16x8*)&as[ra * 64 + pa];
                const int rb = wc * 64 + i * 16 + col;
                const int pb = ((quad + ks * 4) ^ (rb & 7)) * 8;
                bf[i] = *(const bf16x8*)&bs[rb * 64 + pb];
            }
            #pragma unroll
            for (int i = 0; i < 4; ++i)
                #pragma unroll
                for (int j = 0; j < 4; ++j)
                    acc[i][j] = __builtin_amdgcn_mfma_f32_16x16x32_bf16(af[i], bf[j], acc[i][j], 0, 0, 0);
        }

        __builtin_amdgcn_s_barrier();
        if (kt + 2 < nk) {
            DMA(kt + 2, cur);
            asm volatile("s_waitcnt vmcnt(8)" ::: "memory");
        } else {
            asm volatile("s_waitcnt vmcnt(0)" ::: "memory");
        }
        __builtin_amdgcn_s_barrier();
    }

    if (VSPLIT) {
        // (unused in this configuration)
    } else {
        #pragma unroll
        for (int i = 0; i < 4; ++i)
            #pragma unroll
            for (int r = 0; r < 4; ++r) {
                const int m = m0 + wr * 64 + i * 16 + quad * 4 + r;
                #pragma unroll
                for (int j = 0; j < 4; ++j) {
                    const int n = n0 + wc * 64 + j * 16 + col;
                    OutF[(size_t)m * N + n] = acc[i][j][r] + bias[n];
                }
            }
    }
}

// ---------------------------------------------------------------------------
// MFMA flash attention v10 (unchanged, ~68 µs): 1024 blocks (one 128-q
// tile each, 4 waves x 32 q-rows), big-qb first, XCD-grouped; kbias
// prefetched a tile ahead; counted-vmcnt two-barrier pipeline.
// ---------------------------------------------------------------------------
constexpr int PP = 72;           // Ps row stride (bf16)

__global__ __launch_bounds__(256, 3) void attn_mfma(
    const unsigned short* __restrict__ Qp,
    const unsigned short* __restrict__ Kp,
    const unsigned short* __restrict__ Vtp,
    const float* __restrict__ kbias,
    unsigned short* __restrict__ WV)
{
    __shared__ alignas(16) unsigned short Ks [2][64 * 64];  // [key][d], swizzled
    __shared__ alignas(16) unsigned short Vts[2][64 * 64];  // [d][tc], swizzled
    __shared__ alignas(16) __bf16        Ps[4][32 * PP];    // per-wave P (32 rows)

    const int tid  = threadIdx.x;
    const int w    = tid >> 6;       // 0..3
    const int lane = tid & 63;
    const int quad = lane >> 4;
    const int col  = lane & 15;

    // grid decode: 1024 blocks; launch idx mod 8 ~ XCD. XCD x owns bh
    // x*8..x*8+7; qb descends with dispatch order (big blocks first).
    const int gi = blockIdx.x;
    const int j  = gi >> 3;
    const int bh = ((gi & 7) << 3) | (j & 7);
    const int qb = 15 - (j >> 3);
    const int b = bh >> 4, h = bh & 15;

    const unsigned short* Qg = Qp + (size_t)b * TT * CC + (size_t)h * HDD;
    const unsigned short* Kg = Kp + (size_t)bh * TT * HDD;
    const unsigned short* Vg = Vtp + (size_t)bh * 32 * HDD * 64;
    const float* kb_g = kbias + b * TT;

    // staging map: thread -> (row = tid>>3 in 0..31, pos = tid&7);
    // fetched chunk = pos ^ (row&7) so frag reads de-swizzle conflict-free.
    const int srow = tid >> 3;
    const int sch  = (tid & 7) ^ (srow & 7);
    char* KsB  = (char*)&Ks[0][0];
    char* VtsB = (char*)&Vts[0][0];

    const int qw = qb * 128 + w * 32;   // wave's first q row (32 rows)
    const int ntiles = 2 * qb + 2;      // >= 2

    // Q fragments direct from global (A-layout: lane holds Q[row+col][quad*8+j])
    bf16x8 qfa0 = *(const bf16x8*)(Qg + (size_t)(qw + col) * CC + quad * 8);
    bf16x8 qfa1 = *(const bf16x8*)(Qg + (size_t)(qw + col) * CC + 32 + quad * 8);
    bf16x8 qfb0 = *(const bf16x8*)(Qg + (size_t)(qw + 16 + col) * CC + quad * 8);
    bf16x8 qfb1 = *(const bf16x8*)(Qg + (size_t)(qw + 16 + col) * CC + 32 + quad * 8);

    f32x4 o[2][4];
    float l[2][4];
    #pragma unroll
    for (int hh = 0; hh < 2; ++hh)
        #pragma unroll
        for (int t = 0; t < 4; ++t)
            #pragma unroll
            for (int r = 0; r < 4; ++r) o[hh][t][r] = 0.0f;
    #pragma unroll
    for (int hh = 0; hh < 2; ++hh)
        #pragma unroll
        for (int r = 0; r < 4; ++r) l[hh][r] = 0.0f;

    // DMA one 64-key tile (K + Vt, 8KB each) into buffer `buf`
    auto DMA = [&](int tile, int buf) {
        #pragma unroll
        for (int i = 0; i < 2; ++i) {
            __builtin_amdgcn_global_load_lds(
                AS1(Kg + (size_t)(tile * 64 + srow + 32 * i) * HDD + sch * 8),
                AS3(KsB + buf * 8192 + i * 4096 + w * 1024), 16, 0, 0);
            __builtin_amdgcn_global_load_lds(
                AS1(Vg + ((size_t)tile * 64 + srow + 32 * i) * 64 + sch * 8),
                AS3(VtsB + buf * 8192 + i * 4096 + w * 1024), 16, 0, 0);
        }
    };

    // prologue: tiles 0 and 1 in flight; kb for tiles 0 and 1.
    float kbc[4], kbn[4];
    DMA(0, 0);
    #pragma unroll
    for (int t = 0; t < 4; ++t) kbc[t] = kb_g[t * 16 + col];
    DMA(1, 1);
    #pragma unroll
    for (int t = 0; t < 4; ++t) kbn[t] = kb_g[64 + t * 16 + col];
    asm volatile("s_waitcnt vmcnt(8)" ::: "memory");   // tile 0 + kb0 landed
    __builtin_amdgcn_s_barrier();

    for (int it = 0; it < ntiles; ++it) {
        const int kt  = it << 6;
        const int cur = it & 1;

        if (kt <= qw + 31) {  // wave active for this key-tile
            const unsigned short* ksb = &Ks[cur][0];
            const unsigned short* vsb = &Vts[cur][0];

            // --- S = Q K^T + kb (both 16-row halves share K frags) ---
            f32x4 s[2][4];
            #pragma unroll
            for (int t = 0; t < 4; ++t) {
                const int row = t * 16 + col;
                const int c0 = (quad ^ (row & 7)) * 8;
                const int c1 = ((quad + 4) ^ (row & 7)) * 8;
                bf16x8 k0 = *(const bf16x8*)&ksb[row * 64 + c0];
                bf16x8 k1 = *(const bf16x8*)&ksb[row * 64 + c1];
                f32x4 z;
                #pragma unroll
                for (int r = 0; r < 4; ++r) z[r] = kbc[t];
                f32x4 za = __builtin_amdgcn_mfma_f32_16x16x32_bf16(qfa0, k0, z, 0, 0, 0);
                za = __builtin_amdgcn_mfma_f32_16x16x32_bf16(qfa1, k1, za, 0, 0, 0);
                s[0][t] = za;
                f32x4 zb = __builtin_amdgcn_mfma_f32_16x16x32_bf16(qfb0, k0, z, 0, 0, 0);
                zb = __builtin_amdgcn_mfma_f32_16x16x32_bf16(qfb1, k1, zb, 0, 0, 0);
                s[1][t] = zb;
            }

            // --- p = 2^s, causal zero on the wave's edge tiles ---
            const bool needc = (kt + 64 > qw);
            #pragma unroll
            for (int hh = 0; hh < 2; ++hh)
                #pragma unroll
                for (int t = 0; t < 4; ++t) {
                    const int key = kt + t * 16 + col;
                    #pragma unroll
                    for (int r = 0; r < 4; ++r) {
                        float p = __builtin_amdgcn_exp2f(s[hh][t][r]);
                        if (needc && key > qw + hh * 16 + quad * 4 + r) p = 0.0f;
                        l[hh][r] += p;
                        Ps[w][(hh * 16 + quad * 4 + r) * PP + t * 16 + col] = (__bf16)p;
                    }
                }

            // --- PV: O += P V (V frags shared by both halves) ---
            bf16x8 p0a = *(const bf16x8*)&Ps[w][col * PP + quad * 8];
            bf16x8 p1a = *(const bf16x8*)&Ps[w][col * PP + 32 + quad * 8];
            bf16x8 p0b = *(const bf16x8*)&Ps[w][(16 + col) * PP + quad * 8];
            bf16x8 p1b = *(const bf16x8*)&Ps[w][(16 + col) * PP + 32 + quad * 8];
            #pragma unroll
            for (int t = 0; t < 4; ++t) {
                const int row = t * 16 + col;
                const int c0 = (quad ^ (row & 7)) * 8;
                const int c1 = ((quad + 4) ^ (row & 7)) * 8;
                bf16x8 v0 = *(const bf16x8*)&vsb[row * 64 + c0];
                bf16x8 v1 = *(const bf16x8*)&vsb[row * 64 + c1];
                o[0][t] = __builtin_amdgcn_mfma_f32_16x16x32_bf16(p0a, v0, o[0][t], 0, 0, 0);
                o[0][t] = __builtin_amdgcn_mfma_f32_16x16x32_bf16(p1a, v1, o[0][t], 0, 0, 0);
                o[1][t] = __builtin_amdgcn_mfma_f32_16x16x32_bf16(p0b, v0, o[1][t], 0, 0, 0);
                o[1][t] = __builtin_amdgcn_mfma_f32_16x16x32_bf16(p1b, v1, o[1][t], 0, 0, 0);
            }
        }

        // barrier 1: all waves done READING buf[cur] -> safe to overwrite
        __builtin_amdgcn_s_barrier();

        // shift kb regs: next tile's C-init
        #pragma unroll
        for (int t = 0; t < 4; ++t) kbc[t] = kbn[t];

        if (it + 2 < ntiles) {
            DMA(it + 2, cur);   // overwrite just-consumed buffer
            #pragma unroll
            for (int t = 0; t < 4; ++t)
                kbn[t] = kb_g[(it + 2) * 64 + t * 16 + col];
            // wait: tile it+1 (+kb) landed; tile it+2 stays in flight
            asm volatile("s_waitcnt vmcnt(8)" ::: "memory");
        } else {
            asm volatile("s_waitcnt vmcnt(0)" ::: "memory");
        }
        // barrier 2: buf[(it+1)&1] published to all waves
        __builtin_amdgcn_s_barrier();
    }

    // --- final l reduction across 16 col-lanes (keys), write O/l ---
    #pragma unroll
    for (int hh = 0; hh < 2; ++hh) {
        #pragma unroll
        for (int off = 1; off < 16; off <<= 1)
            #pragma unroll
            for (int r = 0; r < 4; ++r)
                l[hh][r] += __shfl_xor(l[hh][r], off);
        #pragma unroll
        for (int r = 0; r < 4; ++r) {
            const float inv = 1.0f / l[hh][r];
            const int q = qw + hh * 16 + quad * 4 + r;
            unsigned short* dst = WV + ((size_t)b * TT + q) * CC + (size_t)h * HDD;
            #pragma unroll
            for (int t = 0; t < 4; ++t)
                dst[t * 16 + col] = f2bf(o[hh][t][r] * inv);
        }
    }
}

// ---------------------------------------------------------------------------
// Launch
// ---------------------------------------------------------------------------
extern "C" void kernel_launch(void* const* d_in, const int* in_sizes, int n_in,
                              void* d_out, int out_size, void* d_ws, size_t ws_size,
                              hipStream_t stream) {
    const float* x     = (const float*)d_in[0]; // (B,T,C)
    const float* amask = (const float*)d_in[1]; // (B,T)
    const float* Wqkv  = (const float*)d_in[2]; // (C,3C)
    const float* bqkv  = (const float*)d_in[3]; // (3C)
    const float* Wout  = (const float*)d_in[4]; // (C,C)
    const float* bout  = (const float*)d_in[5]; // (C)
    float* out = (float*)d_out;                 // (B,T,C)

    const int M = BB * TT; // 8192

    // Workspace: xb 16M | Wqkvt 6M | Woutt 2M | Qp 16M | Kp 16M | Vtp 16M |
    //            wvb 16M | kbias 32K  (total ~88 MB)
    unsigned short* xb    = (unsigned short*)d_ws;
    unsigned short* Wqkvt = xb    + (size_t)M * CC;
    unsigned short* Woutt = Wqkvt + (size_t)C3 * CC;
    unsigned short* Qp    = Woutt + (size_t)CC * CC;
    unsigned short* Kp    = Qp    + (size_t)M * CC;
    unsigned short* Vtp   = Kp    + (size_t)M * CC;
    unsigned short* wvb   = Vtp   + (size_t)M * CC;
    float*          kbias = (float*)(wvb + (size_t)M * CC);

    dim3 blk(256);

    // 0) fused prep: x->bf16, W_qkv^T, W_out^T, kbias
    prep<<<dim3(CAST_BLOCKS + TQKV_BLOCKS + TOUT_BLOCKS + KB_BLOCKS), blk, 0, stream>>>(
        x, Wqkv, Wout, amask, xb, Wqkvt, Woutt, kbias);

    // 1) QKV projection (256x192 tile, 8 waves) -> Qp scaled, Kp packed, Vtp
    gemm_qkv<<<dim3(512), dim3(512), 0, stream>>>(
        xb, Wqkvt, bqkv, Qp, Kp, Vtp);
    // 2) attention: 1024 blocks (bh x 16 q-tiles, big-first, XCD-grouped)
    attn_mfma<<<dim3(1024), dim3(256), 0, stream>>>(
        Qp, Kp, Vtp, kbias, wvb);
    // 3) Output projection (fp32 out)
    gemm_bt_mfma<false><<<dim3(CC / 128, M / 128), blk, 0, stream>>>(
        wvb, Woutt, bout, out, nullptr, nullptr, nullptr, M, CC, CC, 1.0f);
}

// Round 5
// 234.685 us; speedup vs baseline: 1.0550x; 1.0550x over previous
//
#include <hip/hip_runtime.h>
#include <math.h>

// Problem constants (fixed by reference)
constexpr int BB = 4;
constexpr int TT = 2048;
constexpr int CC = 1024;
constexpr int NHH = 16;
constexpr int HDD = 64;    // head dim
constexpr int C3 = 3 * CC; // 3072

typedef __bf16 bf16x8 __attribute__((ext_vector_type(8)));
typedef __bf16 bf16x4 __attribute__((ext_vector_type(4)));
typedef float  f32x4  __attribute__((ext_vector_type(4)));

__device__ __forceinline__ unsigned short f2bf(float x) {
    union { float f; unsigned u; } v; v.f = x;
    unsigned r = v.u + 0x7fffu + ((v.u >> 16) & 1u);  // RNE
    return (unsigned short)(r >> 16);
}

#define AS1(p) ((const __attribute__((address_space(1))) void*)(p))
#define AS3(p) ((__attribute__((address_space(3))) void*)(p))

constexpr float SM2 = 17.312340490667561f;    // 12 * log2(e)

// ---------------------------------------------------------------------------
// prep: (a) x fp32->bf16 cast, (b) W_qkv transpose+cast, (c) W_out
// transpose+cast, (d) kbias = (mask-1)*1e38 - SM2 (fp32) — block-range dispatch.
// ---------------------------------------------------------------------------
constexpr int CAST_BLOCKS = (BB * TT * CC / 4) / 256;          // 8192
constexpr int TQKV_BLOCKS = (C3 / 64) * (CC / 64);             // 768
constexpr int TOUT_BLOCKS = (CC / 64) * (CC / 64);             // 256
constexpr int KB_BLOCKS   = (BB * TT) / 256;                   // 32

__global__ __launch_bounds__(256) void prep(
    const float* __restrict__ x,
    const float* __restrict__ Wqkv,
    const float* __restrict__ Wout,
    const float* __restrict__ amask,
    unsigned short* __restrict__ xb,
    unsigned short* __restrict__ Wqkvt,
    unsigned short* __restrict__ Woutt,
    float* __restrict__ kbias)
{
    __shared__ float tile[64][65];
    const int bid = blockIdx.x;
    const int t = threadIdx.x;

    if (bid < CAST_BLOCKS) {
        const int i = bid * 256 + t;
        float4 v = ((const float4*)x)[i];
        ushort4 o;
        o.x = f2bf(v.x); o.y = f2bf(v.y); o.z = f2bf(v.z); o.w = f2bf(v.w);
        ((ushort4*)xb)[i] = o;
        return;
    }
    if (bid >= CAST_BLOCKS + TQKV_BLOCKS + TOUT_BLOCKS) {
        const int i = (bid - CAST_BLOCKS - TQKV_BLOCKS - TOUT_BLOCKS) * 256 + t;
        kbias[i] = (amask[i] - 1.0f) * 1.0e38f - SM2;
        return;
    }

    const float* src; unsigned short* dst; int R, Cn, r0, c0;
    if (bid < CAST_BLOCKS + TQKV_BLOCKS) {
        const int tb = bid - CAST_BLOCKS;
        src = Wqkv; dst = Wqkvt; R = CC; Cn = C3;
        c0 = (tb % (C3 / 64)) * 64; r0 = (tb / (C3 / 64)) * 64;
    } else {
        const int tb = bid - CAST_BLOCKS - TQKV_BLOCKS;
        src = Wout; dst = Woutt; R = CC; Cn = CC;
        c0 = (tb % (CC / 64)) * 64; r0 = (tb / (CC / 64)) * 64;
    }

    const int lr = t >> 4, lc = (t & 15) * 4;
    #pragma unroll
    for (int s = 0; s < 4; ++s) {
        float4 v = *(const float4*)&src[(size_t)(r0 + lr + s * 16) * Cn + c0 + lc];
        tile[lr + s * 16][lc + 0] = v.x;
        tile[lr + s * 16][lc + 1] = v.y;
        tile[lr + s * 16][lc + 2] = v.z;
        tile[lr + s * 16][lc + 3] = v.w;
    }
    __syncthreads();
    const int oi = t >> 2, oc = (t & 3) * 16;
    unsigned short buf[16];
    #pragma unroll
    for (int u = 0; u < 16; ++u)
        buf[u] = f2bf(tile[oc + u][oi]);
    unsigned short* d = &dst[(size_t)(c0 + oi) * R + r0 + oc];
    *(uint4*)(d + 0) = *(uint4*)&buf[0];
    *(uint4*)(d + 8) = *(uint4*)&buf[8];
}

// ---------------------------------------------------------------------------
// bf16 MFMA GEMM (reverted to verified R3 128x128 structure): BK=64,
// XOR-swizzled global_load_lds, counted-vmcnt double-buffer pipeline
// (DMA kt+2 after barrier-1, vmcnt(8) across barrier-2). 64KB LDS ->
// 2 blocks/CU (cross-block overlap is what the 256x192 variant lost).
// XCD-grouped bijective decode. VSPLIT (QKV): Q->Qp scaled, K->Kp packed,
// V->Vtp transposed. Non-VSPLIT: fp32 Out + bias.
// ---------------------------------------------------------------------------
template<bool VSPLIT>
__global__ __launch_bounds__(256, 2) void gemm_bt_mfma(
    const unsigned short* __restrict__ A,   // [M][K]
    const unsigned short* __restrict__ Bt,  // [N][K]
    const float* __restrict__ bias,
    float* __restrict__ OutF,
    unsigned short* __restrict__ Qp,
    unsigned short* __restrict__ Kp,
    unsigned short* __restrict__ Vtp,
    int M, int N, int K, float qscale)
{
    __shared__ alignas(16) unsigned short As[2][128 * 64];  // 32 KB
    __shared__ alignas(16) unsigned short Bs[2][128 * 64];  // 32 KB

    const int tid  = threadIdx.x;
    const int w    = tid >> 6;
    const int lane = tid & 63;
    const int quad = lane >> 4;
    const int col  = lane & 15;

    // XCD-grouped decode (bijective): each XCD gets a contiguous band of
    // 8 M-tiles.
    const int nX  = gridDim.x;
    const int lin = blockIdx.y * nX + blockIdx.x;
    const int pos = lin >> 3;
    const int mt  = ((lin & 7) << 3) | (pos & 7);
    const int nt  = pos >> 3;
    const int m0 = mt * 128, n0 = nt * 128;
    const int wr = w >> 1, wc = w & 1;

    f32x4 acc[4][4];
    #pragma unroll
    for (int i = 0; i < 4; ++i)
        #pragma unroll
        for (int j = 0; j < 4; ++j)
            #pragma unroll
            for (int r = 0; r < 4; ++r)
                acc[i][j][r] = 0.0f;

    const int srow = tid >> 3;   // 0..31
    const int spos = tid & 7;
    char* AsB = (char*)&As[0][0];
    char* BsB = (char*)&Bs[0][0];

    const int nk = K >> 6;

    auto DMA = [&](int kt, int buf) {
        const int k0 = kt << 6;
        #pragma unroll
        for (int i = 0; i < 4; ++i) {
            const int row = srow + 32 * i;
            const int sch = spos ^ (row & 7);
            __builtin_amdgcn_global_load_lds(
                AS1(A + (size_t)(m0 + row) * K + k0 + sch * 8),
                AS3(AsB + buf * 16384 + i * 4096 + w * 1024), 16, 0, 0);
            __builtin_amdgcn_global_load_lds(
                AS1(Bt + (size_t)(n0 + row) * K + k0 + sch * 8),
                AS3(BsB + buf * 16384 + i * 4096 + w * 1024), 16, 0, 0);
        }
    };

    DMA(0, 0);
    DMA(1, 1);
    asm volatile("s_waitcnt vmcnt(8)" ::: "memory");   // tile 0 landed
    __builtin_amdgcn_s_barrier();

    for (int kt = 0; kt < nk; ++kt) {
        const int cur = kt & 1;
        const unsigned short* as = &As[cur][0];
        const unsigned short* bs = &Bs[cur][0];

        #pragma unroll
        for (int ks = 0; ks < 2; ++ks) {
            bf16x8 af[4], bf[4];
            #pragma unroll
            for (int i = 0; i < 4; ++i) {
                const int ra = wr * 64 + i * 16 + col;
                const int pa = ((quad + ks * 4) ^ (ra & 7)) * 8;
                af[i] = *(const bf16x8*)&as[ra * 64 + pa];
                const int rb = wc * 64 + i * 16 + col;
                const int pb = ((quad + ks * 4) ^ (rb & 7)) * 8;
                bf[i] = *(const bf16x8*)&bs[rb * 64 + pb];
            }
            #pragma unroll
            for (int i = 0; i < 4; ++i)
                #pragma unroll
                for (int j = 0; j < 4; ++j)
                    acc[i][j] = __builtin_amdgcn_mfma_f32_16x16x32_bf16(af[i], bf[j], acc[i][j], 0, 0, 0);
        }

        // barrier 1: all waves done reading buf[cur] -> safe to overwrite
        __builtin_amdgcn_s_barrier();
        if (kt + 2 < nk) {
            DMA(kt + 2, cur);
            asm volatile("s_waitcnt vmcnt(8)" ::: "memory");
        } else {
            asm volatile("s_waitcnt vmcnt(0)" ::: "memory");
        }
        // barrier 2: buf[cur^1] published to all waves
        __builtin_amdgcn_s_barrier();
    }

    if (VSPLIT) {
        if (n0 < CC) {
            // Q region -> Qp[m][C], pre-scaled
            #pragma unroll
            for (int i = 0; i < 4; ++i)
                #pragma unroll
                for (int r = 0; r < 4; ++r) {
                    const int m = m0 + wr * 64 + i * 16 + quad * 4 + r;
                    #pragma unroll
                    for (int j = 0; j < 4; ++j) {
                        const int n = n0 + wc * 64 + j * 16 + col;
                        Qp[(size_t)m * CC + n] = f2bf((acc[i][j][r] + bias[n]) * qscale);
                    }
                }
        } else if (n0 < 2 * CC) {
            // K region -> Kp[bh][t][d]
            #pragma unroll
            for (int i = 0; i < 4; ++i) {
                const int mb   = m0 + wr * 64 + i * 16 + quad * 4;  // + r
                const int bidx = mb >> 11;
                const int tloc = mb & 2047;
                #pragma unroll
                for (int j = 0; j < 4; ++j) {
                    const int n  = n0 + wc * 64 + j * 16 + col;
                    const int hh = (n - CC) >> 6;
                    const int dd = (n - CC) & 63;
                    #pragma unroll
                    for (int r = 0; r < 4; ++r)
                        Kp[(((size_t)bidx * NHH + hh) * TT + tloc + r) * HDD + dd] =
                            f2bf(acc[i][j][r] + bias[n]);
                }
            }
        } else {
            // V region -> Vtp[bh][tile][d][64]
            #pragma unroll
            for (int i = 0; i < 4; ++i) {
                const int mb   = m0 + wr * 64 + i * 16 + quad * 4;  // + r
                const int bidx = mb >> 11;
                const int tloc = mb & 2047;
                const int ktile = tloc >> 6, tc = tloc & 63;
                #pragma unroll
                for (int j = 0; j < 4; ++j) {
                    const int n  = n0 + wc * 64 + j * 16 + col;
                    const int hh = (n - 2 * CC) >> 6;
                    const int dd = (n - 2 * CC) & 63;
                    unsigned short pk[4];
                    #pragma unroll
                    for (int r = 0; r < 4; ++r)
                        pk[r] = f2bf(acc[i][j][r] + bias[n]);
                    *(uint2*)&Vtp[((((size_t)bidx * NHH + hh) * 32 + ktile) * HDD + dd) * 64 + tc] =
                        *(const uint2*)pk;
                }
            }
        }
    } else {
        #pragma unroll
        for (int i = 0; i < 4; ++i)
            #pragma unroll
            for (int r = 0; r < 4; ++r) {
                const int m = m0 + wr * 64 + i * 16 + quad * 4 + r;
                #pragma unroll
                for (int j = 0; j < 4; ++j) {
                    const int n = n0 + wc * 64 + j * 16 + col;
                    OutF[(size_t)m * N + n] = acc[i][j][r] + bias[n];
                }
            }
    }
}

// ---------------------------------------------------------------------------
// MFMA flash attention v11: swapped QK^T (T12-lite). v10 counters showed
// the P LDS round-trip dominating (VALU 49%, 1.08M bank-conflicts from 32
// scalar ds_write_b16 per wave-tile). Computing S^T = mfma(K, Q) uses the
// SAME K/Q registers (K-frag as A, Q-frag as B) but lands P[q=col]
// [key=quad*4+r]: per-lane key-contiguous ->
//   * 8 ds_write_b64 replace 32 ds_write_b16 (conflict-free pattern)
//   * kbias C-init becomes one f32x4 load per t, fed directly to MFMA C
//   * l is one scalar per lane; epilogue = 2 shfl_xor + 4 shfl broadcasts
// PV A-frag reads (2 b128/hh), V reads, output layout unchanged.
// Pipeline (1024 blocks, big-qb first, XCD-grouped, counted-vmcnt
// two-barrier, kb prefetch) carried over from v10.
// ---------------------------------------------------------------------------
constexpr int PP = 72;           // Ps row stride (bf16); 144B: 16B-aligned rows

__global__ __launch_bounds__(256, 3) void attn_mfma(
    const unsigned short* __restrict__ Qp,
    const unsigned short* __restrict__ Kp,
    const unsigned short* __restrict__ Vtp,
    const float* __restrict__ kbias,
    unsigned short* __restrict__ WV)
{
    __shared__ alignas(16) unsigned short Ks [2][64 * 64];  // [key][d], swizzled
    __shared__ alignas(16) unsigned short Vts[2][64 * 64];  // [d][tc], swizzled
    __shared__ alignas(16) __bf16        Ps[4][32 * PP];    // per-wave P[q][key]

    const int tid  = threadIdx.x;
    const int w    = tid >> 6;       // 0..3
    const int lane = tid & 63;
    const int quad = lane >> 4;
    const int col  = lane & 15;

    // grid decode: 1024 blocks; launch idx mod 8 ~ XCD. XCD x owns bh
    // x*8..x*8+7; qb descends with dispatch order (big blocks first).
    const int gi = blockIdx.x;
    const int j  = gi >> 3;
    const int bh = ((gi & 7) << 3) | (j & 7);
    const int qb = 15 - (j >> 3);
    const int b = bh >> 4, h = bh & 15;

    const unsigned short* Qg = Qp + (size_t)b * TT * CC + (size_t)h * HDD;
    const unsigned short* Kg = Kp + (size_t)bh * TT * HDD;
    const unsigned short* Vg = Vtp + (size_t)bh * 32 * HDD * 64;
    const float* kb_g = kbias + b * TT;

    // staging map: thread -> (row = tid>>3 in 0..31, pos = tid&7);
    // fetched chunk = pos ^ (row&7) so frag reads de-swizzle conflict-free.
    const int srow = tid >> 3;
    const int sch  = (tid & 7) ^ (srow & 7);
    char* KsB  = (char*)&Ks[0][0];
    char* VtsB = (char*)&Vts[0][0];

    const int qw = qb * 128 + w * 32;   // wave's first q row (32 rows)
    const int ntiles = 2 * qb + 2;      // >= 2

    // Q fragments direct from global; serve as B-frags for S^T = mfma(K,Q):
    // lane holds Q[qw(+16hh)+col][quad*8+j] = B[k=d][n=q].
    bf16x8 qfa0 = *(const bf16x8*)(Qg + (size_t)(qw + col) * CC + quad * 8);
    bf16x8 qfa1 = *(const bf16x8*)(Qg + (size_t)(qw + col) * CC + 32 + quad * 8);
    bf16x8 qfb0 = *(const bf16x8*)(Qg + (size_t)(qw + 16 + col) * CC + quad * 8);
    bf16x8 qfb1 = *(const bf16x8*)(Qg + (size_t)(qw + 16 + col) * CC + 32 + quad * 8);

    f32x4 o[2][4];
    float l[2] = {0.0f, 0.0f};
    #pragma unroll
    for (int hh = 0; hh < 2; ++hh)
        #pragma unroll
        for (int t = 0; t < 4; ++t)
            #pragma unroll
            for (int r = 0; r < 4; ++r) o[hh][t][r] = 0.0f;

    // DMA one 64-key tile (K + Vt, 8KB each) into buffer `buf`
    auto DMA = [&](int tile, int buf) {
        #pragma unroll
        for (int i = 0; i < 2; ++i) {
            __builtin_amdgcn_global_load_lds(
                AS1(Kg + (size_t)(tile * 64 + srow + 32 * i) * HDD + sch * 8),
                AS3(KsB + buf * 8192 + i * 4096 + w * 1024), 16, 0, 0);
            __builtin_amdgcn_global_load_lds(
                AS1(Vg + ((size_t)tile * 64 + srow + 32 * i) * 64 + sch * 8),
                AS3(VtsB + buf * 8192 + i * 4096 + w * 1024), 16, 0, 0);
        }
    };

    // prologue: tiles 0 and 1 in flight; kb (f32x4 per t, key=t*16+quad*4+r)
    f32x4 kbc[4], kbn[4];
    DMA(0, 0);
    #pragma unroll
    for (int t = 0; t < 4; ++t)
        kbc[t] = *(const f32x4*)&kb_g[t * 16 + quad * 4];
    DMA(1, 1);
    #pragma unroll
    for (int t = 0; t < 4; ++t)
        kbn[t] = *(const f32x4*)&kb_g[64 + t * 16 + quad * 4];
    asm volatile("s_waitcnt vmcnt(8)" ::: "memory");   // tile 0 + kb0 landed
    __builtin_amdgcn_s_barrier();

    for (int it = 0; it < ntiles; ++it) {
        const int kt  = it << 6;
        const int cur = it & 1;

        if (kt <= qw + 31) {  // wave active for this key-tile
            const unsigned short* ksb = &Ks[cur][0];
            const unsigned short* vsb = &Vts[cur][0];

            // --- S^T = K Q^T + kb: lane holds S[q=..+col][key=kt+t*16+quad*4+r]
            f32x4 s[2][4];
            #pragma unroll
            for (int t = 0; t < 4; ++t) {
                const int row = t * 16 + col;
                const int c0 = (quad ^ (row & 7)) * 8;
                const int c1 = ((quad + 4) ^ (row & 7)) * 8;
                bf16x8 k0 = *(const bf16x8*)&ksb[row * 64 + c0];  // A[m=key][d 0..31]
                bf16x8 k1 = *(const bf16x8*)&ksb[row * 64 + c1];  // A[m=key][d 32..63]
                f32x4 za = __builtin_amdgcn_mfma_f32_16x16x32_bf16(k0, qfa0, kbc[t], 0, 0, 0);
                za = __builtin_amdgcn_mfma_f32_16x16x32_bf16(k1, qfa1, za, 0, 0, 0);
                s[0][t] = za;
                f32x4 zb = __builtin_amdgcn_mfma_f32_16x16x32_bf16(k0, qfb0, kbc[t], 0, 0, 0);
                zb = __builtin_amdgcn_mfma_f32_16x16x32_bf16(k1, qfb1, zb, 0, 0, 0);
                s[1][t] = zb;
            }

            // --- p = 2^s, causal zero; pack 4 keys -> one ds_write_b64 ---
            const bool needc = (kt + 64 > qw);
            #pragma unroll
            for (int hh = 0; hh < 2; ++hh) {
                const int q = qw + hh * 16 + col;
                #pragma unroll
                for (int t = 0; t < 4; ++t) {
                    float pv[4];
                    #pragma unroll
                    for (int r = 0; r < 4; ++r) {
                        const int key = kt + t * 16 + quad * 4 + r;
                        float p = __builtin_amdgcn_exp2f(s[hh][t][r]);
                        if (needc && key > q) p = 0.0f;
                        l[hh] += p;
                        pv[r] = p;
                    }
                    bf16x4 pk4 = { (__bf16)pv[0], (__bf16)pv[1],
                                   (__bf16)pv[2], (__bf16)pv[3] };
                    *(bf16x4*)&Ps[w][(hh * 16 + col) * PP + t * 16 + quad * 4] = pk4;
                }
            }

            // --- PV: O += P V; P read back as A-frag (2 b128 per half) ---
            bf16x8 pa0 = *(const bf16x8*)&Ps[w][col * PP + quad * 8];
            bf16x8 pa1 = *(const bf16x8*)&Ps[w][col * PP + 32 + quad * 8];
            bf16x8 pb0 = *(const bf16x8*)&Ps[w][(16 + col) * PP + quad * 8];
            bf16x8 pb1 = *(const bf16x8*)&Ps[w][(16 + col) * PP + 32 + quad * 8];
            #pragma unroll
            for (int t = 0; t < 4; ++t) {
                const int row = t * 16 + col;
                const int c0 = (quad ^ (row & 7)) * 8;
                const int c1 = ((quad + 4) ^ (row & 7)) * 8;
                bf16x8 v0 = *(const bf16x8*)&vsb[row * 64 + c0];
                bf16x8 v1 = *(const bf16x8*)&vsb[row * 64 + c1];
                o[0][t] = __builtin_amdgcn_mfma_f32_16x16x32_bf16(pa0, v0, o[0][t], 0, 0, 0);
                o[0][t] = __builtin_amdgcn_mfma_f32_16x16x32_bf16(pa1, v1, o[0][t], 0, 0, 0);
                o[1][t] = __builtin_amdgcn_mfma_f32_16x16x32_bf16(pb0, v0, o[1][t], 0, 0, 0);
                o[1][t] = __builtin_amdgcn_mfma_f32_16x16x32_bf16(pb1, v1, o[1][t], 0, 0, 0);
            }
        }

        // barrier 1: all waves done READING buf[cur] -> safe to overwrite
        __builtin_amdgcn_s_barrier();

        // shift kb regs: next tile's C-init
        #pragma unroll
        for (int t = 0; t < 4; ++t) kbc[t] = kbn[t];

        if (it + 2 < ntiles) {
            DMA(it + 2, cur);   // overwrite just-consumed buffer
            #pragma unroll
            for (int t = 0; t < 4; ++t)
                kbn[t] = *(const f32x4*)&kb_g[(it + 2) * 64 + t * 16 + quad * 4];
            // wait: tile it+1 (+kb) landed; tile it+2 stays in flight
            asm volatile("s_waitcnt vmcnt(8)" ::: "memory");
        } else {
            asm volatile("s_waitcnt vmcnt(0)" ::: "memory");
        }
        // barrier 2: buf[(it+1)&1] published to all waves
        __builtin_amdgcn_s_barrier();
    }

    // --- l: reduce across quads (lanes sharing col), broadcast per out-row ---
    #pragma unroll
    for (int hh = 0; hh < 2; ++hh) {
        l[hh] += __shfl_xor(l[hh], 16);
        l[hh] += __shfl_xor(l[hh], 32);
    }
    #pragma unroll
    for (int hh = 0; hh < 2; ++hh) {
        #pragma unroll
        for (int r = 0; r < 4; ++r) {
            const float Lr = __shfl(l[hh], (lane & 48) | (quad * 4 + r));
            const float inv = 1.0f / Lr;
            const int q = qw + hh * 16 + quad * 4 + r;
            unsigned short* dst = WV + ((size_t)b * TT + q) * CC + (size_t)h * HDD;
            #pragma unroll
            for (int t = 0; t < 4; ++t)
                dst[t * 16 + col] = f2bf(o[hh][t][r] * inv);
        }
    }
}

// ---------------------------------------------------------------------------
// Launch
// ---------------------------------------------------------------------------
extern "C" void kernel_launch(void* const* d_in, const int* in_sizes, int n_in,
                              void* d_out, int out_size, void* d_ws, size_t ws_size,
                              hipStream_t stream) {
    const float* x     = (const float*)d_in[0]; // (B,T,C)
    const float* amask = (const float*)d_in[1]; // (B,T)
    const float* Wqkv  = (const float*)d_in[2]; // (C,3C)
    const float* bqkv  = (const float*)d_in[3]; // (3C)
    const float* Wout  = (const float*)d_in[4]; // (C,C)
    const float* bout  = (const float*)d_in[5]; // (C)
    float* out = (float*)d_out;                 // (B,T,C)

    const int M = BB * TT; // 8192

    // Workspace: xb 16M | Wqkvt 6M | Woutt 2M | Qp 16M | Kp 16M | Vtp 16M |
    //            wvb 16M | kbias 32K  (total ~88 MB)
    unsigned short* xb    = (unsigned short*)d_ws;
    unsigned short* Wqkvt = xb    + (size_t)M * CC;
    unsigned short* Woutt = Wqkvt + (size_t)C3 * CC;
    unsigned short* Qp    = Woutt + (size_t)CC * CC;
    unsigned short* Kp    = Qp    + (size_t)M * CC;
    unsigned short* Vtp   = Kp    + (size_t)M * CC;
    unsigned short* wvb   = Vtp   + (size_t)M * CC;
    float*          kbias = (float*)(wvb + (size_t)M * CC);

    dim3 blk(256);

    // 0) fused prep: x->bf16, W_qkv^T, W_out^T, kbias
    prep<<<dim3(CAST_BLOCKS + TQKV_BLOCKS + TOUT_BLOCKS + KB_BLOCKS), blk, 0, stream>>>(
        x, Wqkv, Wout, amask, xb, Wqkvt, Woutt, kbias);

    // 1) QKV projection -> Qp (scaled by 0.125*log2e), Kp packed, Vtp transposed
    gemm_bt_mfma<true><<<dim3(C3 / 128, M / 128), blk, 0, stream>>>(
        xb, Wqkvt, bqkv, nullptr, Qp, Kp, Vtp, M, C3, CC, 0.18033688011112043f);
    // 2) attention: 1024 blocks (bh x 16 q-tiles, big-first, XCD-grouped)
    attn_mfma<<<dim3(1024), dim3(256), 0, stream>>>(
        Qp, Kp, Vtp, kbias, wvb);
    // 3) Output projection (fp32 out)
    gemm_bt_mfma<false><<<dim3(CC / 128, M / 128), blk, 0, stream>>>(
        wvb, Woutt, bout, out, nullptr, nullptr, nullptr, M, CC, CC, 1.0f);
}